// Round 5
// baseline (3391.027 us; speedup 1.0000x reference)
//
#include <hip/hip_runtime.h>
#include <cstdint>

#define B_   128
#define T_   30
#define F_   2048
#define E_   512
#define H_   512
#define A_   512
#define CD_  128
#define CV_  64
#define V_   10000
#define VP_  10112
#define NN_  49
#define G4_  2048
#define LCAP_ 31
#define NBLK_ 256
#define NTH_  512

typedef __attribute__((ext_vector_type(4))) float f32x4;
typedef _Float16 h2v __attribute__((ext_vector_type(2)));
typedef _Float16 h8v __attribute__((ext_vector_type(8)));

__device__ __forceinline__ float fdot2f(h2v a, h2v b, float c) {
#if __has_builtin(__builtin_amdgcn_fdot2)
  return __builtin_amdgcn_fdot2(a, b, c, false);
#else
  return c + (float)a[0]*(float)b[0] + (float)a[1]*(float)b[1];
#endif
}
__device__ __forceinline__ float tanh_f(float x) {
  x = fminf(fmaxf(x, -15.f), 15.f);
  float e = __expf(2.f * x);
  return __fdividef(e - 1.f, e + 1.f);
}
__device__ __forceinline__ float sig_f(float x) {
  return __fdividef(1.f, 1.f + __expf(-x));
}

// ================= fp16 MFMA GEMM: C = A(M,K) @ B(N,K)^T (+bias) =================
// OMODE: 0=f32 natural, 1=fp16 natural, 2=attWr scatter, 3=wepr scatter, 4=fp16 tanh
template<int OMODE, int BIAS>
__global__ __launch_bounds__(256)
void gemm_h16(const _Float16* __restrict__ A, int lda,
              const _Float16* __restrict__ B, int ldb,
              const float* __restrict__ bias,
              void* __restrict__ Cv, int ldc, int Nreal, int K) {
  __shared__ _Float16 As[128 * 32];
  __shared__ _Float16 Bs[128 * 32];
  const int tid = threadIdx.x;
  const int m0 = blockIdx.y * 128, n0 = blockIdx.x * 128;
  const int lane = tid & 63, wid = tid >> 6;
  const int wm = (wid >> 1) * 64, wn = (wid & 1) * 64;
  f32x4 acc[4][4] = {};
  const int lr = tid >> 2;
  const int lc = (tid & 3) * 8;
  const _Float16* Ag  = A + (size_t)(m0 + lr) * lda + lc;
  const _Float16* Ag2 = Ag + (size_t)64 * lda;
  const _Float16* Bg  = B + (size_t)(n0 + lr) * ldb + lc;
  const _Float16* Bg2 = Bg + (size_t)64 * ldb;
  auto* lAs = (__attribute__((address_space(3))) char*)As;
  auto* lBs = (__attribute__((address_space(3))) char*)Bs;
  const int ldst = lr * 64 + (tid & 3) * 16;
  const int ar = wm + (lane & 15);
  const int br = wn + (lane & 15);
  const int kc = (lane >> 4) * 8;
  for (int k0 = 0; k0 < K; k0 += 32) {
    __builtin_amdgcn_global_load_lds((const __attribute__((address_space(1))) char*)(Ag  + k0), lAs + ldst,        16, 0, 0);
    __builtin_amdgcn_global_load_lds((const __attribute__((address_space(1))) char*)(Ag2 + k0), lAs + 4096 + ldst, 16, 0, 0);
    __builtin_amdgcn_global_load_lds((const __attribute__((address_space(1))) char*)(Bg  + k0), lBs + ldst,        16, 0, 0);
    __builtin_amdgcn_global_load_lds((const __attribute__((address_space(1))) char*)(Bg2 + k0), lBs + 4096 + ldst, 16, 0, 0);
    __syncthreads();
    h8v af[4], bfr[4];
#pragma unroll
    for (int i = 0; i < 4; ++i) {
      af[i]  = *(const h8v*)&As[(ar + i * 16) * 32 + kc];
      bfr[i] = *(const h8v*)&Bs[(br + i * 16) * 32 + kc];
    }
#pragma unroll
    for (int i = 0; i < 4; ++i)
#pragma unroll
      for (int j = 0; j < 4; ++j)
        acc[i][j] = __builtin_amdgcn_mfma_f32_16x16x32_f16(af[i], bfr[j], acc[i][j], 0, 0, 0);
    __syncthreads();
  }
  const int orow = m0 + wm + (lane >> 4) * 4;
  const int ocol = n0 + wn + (lane & 15);
#pragma unroll
  for (int j = 0; j < 4; ++j) {
    const int col = ocol + j * 16;
    if ((OMODE == 0 || OMODE == 1 || OMODE == 4) && col >= Nreal) continue;
    const float bv = BIAS ? bias[col] : 0.f;
#pragma unroll
    for (int i = 0; i < 4; ++i) {
#pragma unroll
      for (int r = 0; r < 4; ++r) {
        const int row = orow + i * 16 + r;
        const float v = acc[i][j][r] + bv;
        if (OMODE == 0) {
          ((float*)Cv)[(size_t)row * ldc + col] = v;
        } else if (OMODE == 1) {
          ((_Float16*)Cv)[(size_t)row * ldc + col] = (_Float16)v;
        } else if (OMODE == 4) {
          ((_Float16*)Cv)[(size_t)row * ldc + col] = (_Float16)tanh_f(v);
        } else if (OMODE == 2) {
          // attWr[g][b][n][q*2+jl] : row = b*49+n, col = q*512 + 2g + jl
          const int b = row / NN_, n = row - b * NN_;
          const int q = col >> 9, rem = col & 511, gg = rem >> 1, jl = rem & 1;
          ((_Float16*)Cv)[((((size_t)gg * B_ + b) * NN_ + n) << 3) + q * 2 + jl] = (_Float16)v;
        } else if (OMODE == 3) {
          // wepr[g][t][b][q*2+jl] : row = b*30+t
          const int b = row / T_, tt = row - b * T_;
          const int q = col >> 9, rem = col & 511, gg = rem >> 1, jl = rem & 1;
          ((_Float16*)Cv)[((((size_t)gg * T_ + tt) * B_ + b) << 3) + q * 2 + jl] = (_Float16)v;
        }
      }
    }
  }
}

// ================= fp32 GEMM (base) =================
template<int ACT>
__global__ __launch_bounds__(256)
void gemm_nt(const float* __restrict__ A, int lda,
             const float* __restrict__ Bt, int ldb,
             const float* __restrict__ bias,
             float* __restrict__ C, int ldc,
             int M, int N, int K) {
  __shared__ float As[16][64];
  __shared__ float Bs[16][64];
  const int tid = threadIdx.x;
  const int tx = tid & 15, ty = tid >> 4;
  const int n0 = blockIdx.x * 64, m0 = blockIdx.y * 64;
  const int lrow = tid >> 2, lkq = (tid & 3) << 2;
  const bool aval = (m0 + lrow) < M;
  const bool bval = (n0 + lrow) < N;
  const float* Ap = A  + (size_t)(m0 + lrow) * lda + lkq;
  const float* Bp = Bt + (size_t)(n0 + lrow) * ldb + lkq;
  float acc[4][4] = {};
  for (int k0 = 0; k0 < K; k0 += 16) {
    float4 av = make_float4(0.f,0.f,0.f,0.f), bv = make_float4(0.f,0.f,0.f,0.f);
    if (aval) av = *(const float4*)(Ap + k0);
    if (bval) bv = *(const float4*)(Bp + k0);
    __syncthreads();
    As[lkq+0][lrow]=av.x; As[lkq+1][lrow]=av.y; As[lkq+2][lrow]=av.z; As[lkq+3][lrow]=av.w;
    Bs[lkq+0][lrow]=bv.x; Bs[lkq+1][lrow]=bv.y; Bs[lkq+2][lrow]=bv.z; Bs[lkq+3][lrow]=bv.w;
    __syncthreads();
#pragma unroll
    for (int k = 0; k < 16; ++k) {
      float a4[4], b4[4];
#pragma unroll
      for (int i = 0; i < 4; ++i) a4[i] = As[k][ty*4+i];
#pragma unroll
      for (int j = 0; j < 4; ++j) b4[j] = Bs[k][tx*4+j];
#pragma unroll
      for (int i = 0; i < 4; ++i)
#pragma unroll
        for (int j = 0; j < 4; ++j) acc[i][j] += a4[i]*b4[j];
    }
  }
#pragma unroll
  for (int i = 0; i < 4; ++i) {
    int m = m0 + ty*4 + i;
    if (m >= M) continue;
#pragma unroll
    for (int j = 0; j < 4; ++j) {
      int n = n0 + tx*4 + j;
      if (n >= N) continue;
      float v = acc[i][j];
      if (bias) v += bias[n];
      if (ACT == 1) v = tanhf(v);
      C[(size_t)m * ldc + n] = v;
    }
  }
}

// ---------------- att_feats (B,F,49) -> att_th (B,49,F) fp16 ----------------
__global__ __launch_bounds__(256)
void transpose_att(const float* __restrict__ af, _Float16* __restrict__ att_th) {
  __shared__ float s[64 * NN_];
  const int b = blockIdx.y, f0 = blockIdx.x * 64;
  const float* src = af + (size_t)b * F_ * NN_ + (size_t)f0 * NN_;
  for (int i = threadIdx.x; i < 64 * NN_; i += 256) s[i] = src[i];
  __syncthreads();
  _Float16* dst = att_th + (size_t)b * NN_ * F_ + f0;
  for (int i = threadIdx.x; i < NN_ * 64; i += 256) {
    int n = i >> 6, j = i & 63;
    dst[(size_t)n * F_ + j] = (_Float16)s[j * NN_ + n];
  }
}

__global__ void pack_h16(const float* __restrict__ src, int src_ld, int c0,
                         _Float16* __restrict__ dst, int C, int R, int Rpad) {
  int i = blockIdx.x * 256 + threadIdx.x;
  if (i >= Rpad * C) return;
  int r = i / C, c = i - r * C;
  float v = (r < R) ? src[(size_t)r * src_ld + c0 + c] : 0.f;
  dst[i] = (_Float16)v;
}

// whhr[g][p][k], p = q*2+jl -> w_hh row q*512 + 2g + jl
__global__ void repack_whh(const float* __restrict__ w_hh, _Float16* __restrict__ whhr) {
  int i = blockIdx.x * 256 + threadIdx.x;
  if (i >= 256 * 8 * 512) return;
  int k = i & 511, p = (i >> 9) & 7, g = i >> 12;
  int q = p >> 1, jl = p & 1;
  whhr[i] = (_Float16)w_hh[(size_t)(q * 512 + 2 * g + jl) * H_ + k];
}
// wa_r[g][a1][k] -> att_hw row 2g+a1
__global__ void repack_wa(const float* __restrict__ att_hw, _Float16* __restrict__ wa_r) {
  int i = blockIdx.x * 256 + threadIdx.x;
  if (i >= 256 * 2 * 512) return;
  int k = i & 511, a1 = (i >> 9) & 1, g = i >> 10;
  wa_r[i] = (_Float16)att_hw[(size_t)(2 * g + a1) * H_ + k];
}

__global__ __launch_bounds__(128)
void count_embed_k(const float* __restrict__ cv, const float* __restrict__ w1,
                   const float* __restrict__ b1, const float* __restrict__ w2,
                   const float* __restrict__ b2, float* __restrict__ ce) {
  const int b = blockIdx.x, tid = threadIdx.x;
  __shared__ float s_cv[CV_], s_h[CD_];
  if (tid < CV_) s_cv[tid] = cv[b * CV_ + tid];
  __syncthreads();
  float acc = b1[tid];
  for (int k = 0; k < CV_; ++k) acc += s_cv[k] * w1[tid * CV_ + k];
  s_h[tid] = fmaxf(acc, 0.f);
  __syncthreads();
  float acc2 = b2[tid];
  for (int k = 0; k < CD_; ++k) acc2 += s_h[k] * w2[tid * CD_ + k];
  ce[b * CD_ + tid] = acc2;
}

__global__ __launch_bounds__(128)
void gather_we(const int* __restrict__ captions, const float* __restrict__ embed_w,
               _Float16* __restrict__ we_h) {
  const int r = blockIdx.x;
  const int b = r / T_, t = r - b * T_;
  const int idx = captions[b * LCAP_ + t];
  const float4 v = ((const float4*)(embed_w + (size_t)idx * E_))[threadIdx.x];
  _Float16 o[4] = {(_Float16)v.x, (_Float16)v.y, (_Float16)v.z, (_Float16)v.w};
  *(h2v*)(we_h + (size_t)r * E_ + threadIdx.x * 4)     = *(h2v*)&o[0];
  *(h2v*)(we_h + (size_t)r * E_ + threadIdx.x * 4 + 2) = *(h2v*)&o[2];
}

__global__ void addvec_k(const float* __restrict__ a, const float* __restrict__ b,
                         float* __restrict__ o, int n) {
  int i = blockIdx.x * 256 + threadIdx.x;
  if (i < n) o[i] = a[i] + b[i];
}
__global__ void zero_k(float* __restrict__ p, int n) {
  int i = blockIdx.x * 256 + threadIdx.x;
  if (i < n) p[i] = 0.f;
}

// =================== column-parallel persistent seq loop ===================
// LDS carve (bytes)
#define OFF_AP   0        // attproj_s: 49*512 fp16 (50176)
#define OFF_HS   50176    // h_s: 32 rows x 514 fp16 (32896)
#define OFF_WHH  83072    // whh_s: [8][512] fp16 (8192)
#define OFF_WA   91264    // wa_s: [2][512] fp16 (2048)
#define OFF_PACC 93312    // pacc: [128][4][8] f32 (16384)
#define OFF_BASE 109696   // base_s: [8][128] f32 (4096)
#define OFF_GACC 113792   // gacc: [8][128] f32 (4096)
#define OFF_HP   117888   // s_hp: [512] f32 (2048)
#define OFF_CS   119936   // c_s: [2][128] f32 (1024)
#define OFF_SC   120960   // s_sc: [64] f32
#define OFF_AL   121216   // (spare)
#define SEQ_LDS  121472

__device__ __forceinline__ void gridbar(unsigned* bar, int& gen) {
  __syncthreads();
  if (threadIdx.x == 0) {
    __threadfence();
    __hip_atomic_fetch_add(bar, 1u, __ATOMIC_RELAXED, __HIP_MEMORY_SCOPE_AGENT);
    const unsigned target = (unsigned)(++gen) * (unsigned)NBLK_;
    while (__hip_atomic_load(bar, __ATOMIC_RELAXED, __HIP_MEMORY_SCOPE_AGENT) < target)
      __builtin_amdgcn_s_sleep(2);
    __threadfence();
  }
  __syncthreads();
}

__global__ __launch_bounds__(NTH_)
void seq_loop(const _Float16* __restrict__ whhr,    // [256][8][512]
              const _Float16* __restrict__ wa_r,    // [256][2][512]
              const float* __restrict__ base_glob,  // [128][2048]
              const _Float16* __restrict__ attproj, // [128*49][512]
              const float* __restrict__ alpha_w, const float* __restrict__ alpha_b,
              const float* __restrict__ att_hb,
              const _Float16* __restrict__ attWr,   // [256][128][49][8]
              const _Float16* __restrict__ wepr,    // [256][30][128][8]
              _Float16* __restrict__ h_glob,        // [2][128][512]
              float* __restrict__ hp_glob,          // [128][512]
              float* __restrict__ alpha_glob,       // [128][64]
              _Float16* __restrict__ H_all,         // [B*T][512]
              float* __restrict__ out_alpha,        // [128][30][49]
              unsigned* __restrict__ bar) {
  extern __shared__ char smem[];
  _Float16* ap_s  = (_Float16*)(smem + OFF_AP);
  _Float16* h_s   = (_Float16*)(smem + OFF_HS);
  _Float16* whh_s = (_Float16*)(smem + OFF_WHH);
  _Float16* wa_s  = (_Float16*)(smem + OFF_WA);
  float* pacc   = (float*)(smem + OFF_PACC);
  float* base_s = (float*)(smem + OFF_BASE);
  float* gacc   = (float*)(smem + OFF_GACC);
  float* s_hp   = (float*)(smem + OFF_HP);
  float* c_s    = (float*)(smem + OFF_CS);
  float* s_sc   = (float*)(smem + OFF_SC);

  const int g = blockIdx.x, tid = threadIdx.x;
  const int lane = tid & 63, wv = tid >> 6;

  // ---- prologue: fill LDS slices ----
  if (tid < 512) ((h8v*)whh_s)[tid] = ((const h8v*)(whhr + (size_t)g * 8 * 512))[tid];
  if (tid < 128) ((h8v*)wa_s)[tid]  = ((const h8v*)(wa_r + (size_t)g * 2 * 512))[tid];
  for (int it = tid; it < 1024; it += NTH_) {
    const int p = it & 7, b = it >> 3;
    const int q = p >> 1, jl = p & 1;
    base_s[p * 128 + b] = base_glob[(size_t)b * G4_ + q * 512 + 2 * g + jl];
  }
  if (tid < 256) c_s[tid] = 0.f;
  if (g < B_) {
    const h8v* src = (const h8v*)(attproj + (size_t)g * NN_ * A_);
    for (int i = tid; i < NN_ * A_ / 8; i += NTH_) ((h8v*)ap_s)[i] = src[i];
  }
  float aw8[8];
#pragma unroll
  for (int i = 0; i < 8; ++i) aw8[i] = alpha_w[lane + 64 * i];
  const float ab  = alpha_b[0];
  const float ahb = att_hb[2 * g + (tid >> 8)];
  __syncthreads();
  int gen = 0;

  for (int t = 0; t < T_; ++t) {
    const _Float16* h_rd = h_glob + (size_t)(t & 1) * (B_ * H_);
    _Float16* h_wr = h_glob + (size_t)((t + 1) & 1) * (B_ * H_);
    // ---- P1: hp[b][2g+a1] = att_hb + h . att_hw  (4 chunks of 32 b) ----
    {
      const int k8 = tid & 7, b5 = (tid >> 3) & 31, a1 = tid >> 8;
      for (int c = 0; c < 4; ++c) {
        __syncthreads();
        const uint* src = (const uint*)(h_rd + (size_t)c * 32 * H_);
#pragma unroll
        for (int i = 0; i < 16; ++i) {
          const int m = tid + i * NTH_;
          ((uint*)h_s)[(m >> 8) * 257 + (m & 255)] = src[m];
        }
        __syncthreads();
        float acc = 0.f;
        const h2v* hrow = (const h2v*)(h_s + b5 * 514);
        const h2v* wrow = (const h2v*)(wa_s + a1 * 512);
#pragma unroll
        for (int kk = 0; kk < 32; ++kk)
          acc = fdot2f(hrow[k8 * 32 + kk], wrow[k8 * 32 + kk], acc);
        acc += __shfl_xor(acc, 1);
        acc += __shfl_xor(acc, 2);
        acc += __shfl_xor(acc, 4);
        if (k8 == 0) hp_glob[(size_t)(c * 32 + b5) * A_ + 2 * g + a1] = acc + ahb;
      }
    }
    gridbar(bar, gen);
    // ---- P2: scores + softmax (blocks g<128, b = g) ----
    if (g < B_) {
      if (tid < A_) s_hp[tid] = hp_glob[(size_t)g * A_ + tid];
      __syncthreads();
      for (int n = wv; n < NN_; n += 8) {
        float s = 0.f;
#pragma unroll
        for (int i = 0; i < 8; ++i) {
          const int a = lane + 64 * i;
          const float x = (float)ap_s[n * A_ + a] + s_hp[a];
          const float e = __expf(2.f * fminf(fmaxf(x, -15.f), 15.f));
          s += __fdividef(e - 1.f, e + 1.f) * aw8[i];
        }
#pragma unroll
        for (int off = 32; off > 0; off >>= 1) s += __shfl_xor(s, off);
        if (lane == 0) s_sc[n] = s + ab;
      }
      __syncthreads();
      if (wv == 0) {
        float v = (lane < NN_) ? s_sc[lane] : -3.0e38f;
        float m = v;
#pragma unroll
        for (int off = 32; off > 0; off >>= 1) m = fmaxf(m, __shfl_xor(m, off));
        float e = (lane < NN_) ? __expf(v - m) : 0.f;
        float ssum = e;
#pragma unroll
        for (int off = 32; off > 0; off >>= 1) ssum += __shfl_xor(ssum, off);
        const float a = __fdividef(e, ssum);
        if (lane < NN_) {
          alpha_glob[(size_t)g * 64 + lane] = a;
          out_alpha[((size_t)g * T_ + t) * NN_ + lane] = a;
        }
      }
    }
    gridbar(bar, gen);
    // ---- P3a: alpha @ attW partials ----
    {
      const int nq = tid & 3, b = tid >> 2;
      f32x4 p0 = {0,0,0,0}, p1 = {0,0,0,0};
      const float* arow = alpha_glob + (size_t)b * 64;
      const _Float16* wrow = attWr + (((size_t)g * B_ + b) * NN_) * 8;
      for (int n = nq; n < NN_; n += 4) {
        const float al = arow[n];
        const h8v w = *(const h8v*)(wrow + (size_t)n * 8);
#pragma unroll
        for (int i = 0; i < 4; ++i) { p0[i] += al * (float)w[i]; p1[i] += al * (float)w[4+i]; }
      }
      float* pr = pacc + ((size_t)b * 4 + nq) * 8;
      *(f32x4*)pr = p0; *(f32x4*)(pr + 4) = p1;
    }
    __syncthreads();
    // ---- P3b: gacc = reduce(pacc) + base + we_proj[t] ----
    {
      const _Float16* wep = wepr + (((size_t)g * T_ + t) * B_) * 8;
#pragma unroll
      for (int e = 0; e < 2; ++e) {
        const int item = tid * 2 + e;
        const int p = item & 7, b = item >> 3;
        float s = base_s[p * 128 + b] + (float)wep[(size_t)b * 8 + p];
        const float* pr = pacc + (size_t)b * 32 + p;
#pragma unroll
        for (int nq = 0; nq < 4; ++nq) s += pr[nq * 8];
        gacc[p * 128 + b] = s;
      }
    }
    __syncthreads();
    // ---- P3c: h @ whh (4 chunks of 32 b) ----
    {
      const int kh = tid & 1, b5 = (tid >> 1) & 31, p3 = tid >> 6;
      for (int c = 0; c < 4; ++c) {
        __syncthreads();
        const uint* src = (const uint*)(h_rd + (size_t)c * 32 * H_);
#pragma unroll
        for (int i = 0; i < 16; ++i) {
          const int m = tid + i * NTH_;
          ((uint*)h_s)[(m >> 8) * 257 + (m & 255)] = src[m];
        }
        __syncthreads();
        float acc = 0.f;
        const h2v* hrow = (const h2v*)(h_s + b5 * 514);
        const h2v* wrow = (const h2v*)(whh_s + p3 * 512);
#pragma unroll 16
        for (int kk = 0; kk < 128; ++kk)
          acc = fdot2f(hrow[kh * 128 + kk], wrow[kh * 128 + kk], acc);
        acc += __shfl_xor(acc, 1);
        if (kh == 0) gacc[p3 * 128 + c * 32 + b5] += acc;
      }
    }
    __syncthreads();
    // ---- P3d: LSTM cell for j = 2g+jl, all b ----
    if (tid < 256) {
      const int jl = tid & 1, b = tid >> 1;
      const float gi = gacc[(0 + jl) * 128 + b];
      const float gf = gacc[(2 + jl) * 128 + b];
      const float gg = gacc[(4 + jl) * 128 + b];
      const float go = gacc[(6 + jl) * 128 + b];
      const float si = sig_f(gi), sf = sig_f(gf), so = sig_f(go);
      float c = c_s[jl * 128 + b];
      c = sf * c + si * tanh_f(gg);
      c_s[jl * 128 + b] = c;
      const float hn = so * tanh_f(c);
      h_wr[(size_t)b * H_ + 2 * g + jl] = (_Float16)hn;
      H_all[((size_t)b * T_ + t) * H_ + 2 * g + jl] = (_Float16)hn;
    }
    gridbar(bar, gen);
  }
}

extern "C" void kernel_launch(void* const* d_in, const int* in_sizes, int n_in,
                              void* d_out, int out_size, void* d_ws, size_t ws_size,
                              hipStream_t stream) {
  const float* att_feats  = (const float*)d_in[0];
  const float* fc_feats   = (const float*)d_in[1];
  const int*   captions   = (const int*)  d_in[2];
  const float* count_vecs = (const float*)d_in[3];
  const float* embed_w    = (const float*)d_in[4];
  const float* cm_w1      = (const float*)d_in[5];
  const float* cm_b1      = (const float*)d_in[6];
  const float* cm_w2      = (const float*)d_in[7];
  const float* cm_b2      = (const float*)d_in[8];
  const float* att_hw     = (const float*)d_in[9];
  const float* att_hb     = (const float*)d_in[10];
  const float* att_fw     = (const float*)d_in[11];
  const float* att_fb     = (const float*)d_in[12];
  const float* alpha_w    = (const float*)d_in[13];
  const float* alpha_b    = (const float*)d_in[14];
  const float* fcproj_w   = (const float*)d_in[15];
  const float* fcproj_b   = (const float*)d_in[16];
  const float* w_ih       = (const float*)d_in[17];
  const float* b_ih       = (const float*)d_in[18];
  const float* w_hh       = (const float*)d_in[19];
  const float* b_hh       = (const float*)d_in[20];
  const float* fc_w       = (const float*)d_in[21];
  const float* fc_b       = (const float*)d_in[22];
  float* out = (float*)d_out;

  char* wsb = (char*)d_ws;
  size_t off = 0;
  auto nxt = [&](size_t bytes) { char* p = wsb + off; off += (bytes + 255) & ~(size_t)255; return p; };
  _Float16* att_th    = (_Float16*)nxt((size_t)B_*NN_*F_*2);
  _Float16* attproj_h = (_Float16*)nxt((size_t)B_*NN_*A_*2);
  _Float16* we_h      = (_Float16*)nxt((size_t)B_*T_*E_*2);
  _Float16* H_all_h   = (_Float16*)nxt((size_t)B_*T_*H_*2);
  _Float16* w_ihF_h   = (_Float16*)nxt((size_t)G4_*F_*2);
  _Float16* w_ih0_h   = (_Float16*)nxt((size_t)G4_*E_*2);
  _Float16* fc_w_h    = (_Float16*)nxt((size_t)VP_*H_*2);
  _Float16* att_fw_h  = (_Float16*)nxt((size_t)A_*F_*2);
  _Float16* fcfeat_h  = (_Float16*)nxt((size_t)B_*F_*2);
  _Float16* fcproj_h  = (_Float16*)nxt((size_t)H_*F_*2);
  _Float16* attWr     = (_Float16*)nxt((size_t)256*B_*NN_*8*2);
  _Float16* wepr      = (_Float16*)nxt((size_t)256*T_*B_*8*2);
  _Float16* whhr      = (_Float16*)nxt((size_t)256*8*512*2);
  _Float16* wa_r      = (_Float16*)nxt((size_t)256*2*512*2);
  _Float16* h_glob    = (_Float16*)nxt((size_t)2*B_*H_*2);
  float*    ce        = (float*)nxt((size_t)B_*CD_*4);
  float*    bsum      = (float*)nxt((size_t)G4_*4);
  float*    base_glob = (float*)nxt((size_t)B_*G4_*4);
  float*    hp_glob   = (float*)nxt((size_t)B_*A_*4);
  float*    alpha_g   = (float*)nxt((size_t)B_*64*4);
  unsigned* bar       = (unsigned*)nxt(256);
  if (off > ws_size) return;

  const size_t ALPHA_OFF = (size_t)B_ * T_ * V_;

  // ---- packs & repacks ----
  transpose_att<<<dim3(F_/64, B_), 256, 0, stream>>>(att_feats, att_th);
  pack_h16<<<((size_t)B_*F_ + 255)/256, 256, 0, stream>>>(fc_feats, F_, 0, fcfeat_h, F_, B_, B_);
  pack_h16<<<((size_t)H_*F_ + 255)/256, 256, 0, stream>>>(fcproj_w, F_, 0, fcproj_h, F_, H_, H_);
  pack_h16<<<((size_t)G4_*F_ + 255)/256, 256, 0, stream>>>(w_ih, E_+F_+CD_, E_, w_ihF_h, F_, G4_, G4_);
  pack_h16<<<((size_t)G4_*E_ + 255)/256, 256, 0, stream>>>(w_ih, E_+F_+CD_, 0, w_ih0_h, E_, G4_, G4_);
  pack_h16<<<((size_t)A_*F_ + 255)/256, 256, 0, stream>>>(att_fw, F_, 0, att_fw_h, F_, A_, A_);
  pack_h16<<<((size_t)VP_*H_ + 255)/256, 256, 0, stream>>>(fc_w, H_, 0, fc_w_h, H_, V_, VP_);
  repack_whh<<<(256*8*512 + 255)/256, 256, 0, stream>>>(w_hh, whhr);
  repack_wa<<<(256*2*512 + 255)/256, 256, 0, stream>>>(att_hw, wa_r);
  count_embed_k<<<B_, 128, 0, stream>>>(count_vecs, cm_w1, cm_b1, cm_w2, cm_b2, ce);
  addvec_k<<<(G4_ + 255)/256, 256, 0, stream>>>(b_ih, b_hh, bsum, G4_);
  gather_we<<<B_ * T_, 128, 0, stream>>>(captions, embed_w, we_h);
  zero_k<<<1, 64, 0, stream>>>((float*)bar, 64);

  // base = ce @ w_ih[:,E+F:]^T + (b_ih+b_hh)
  gemm_nt<0><<<dim3(G4_/64, B_/64), 256, 0, stream>>>(ce, CD_, w_ih + E_ + F_, E_+F_+CD_,
                                                      bsum, base_glob, G4_, B_, G4_, CD_);
  // attproj (fp16, +att_fb)
  gemm_h16<1,1><<<dim3(A_/128, (B_*NN_)/128), 256, 0, stream>>>(
      att_th, F_, att_fw_h, F_, att_fb, attproj_h, A_, A_, F_);
  // attW -> scattered attWr
  gemm_h16<2,0><<<dim3(G4_/128, (B_*NN_)/128), 256, 0, stream>>>(
      att_th, F_, w_ihF_h, F_, nullptr, attWr, G4_, G4_, F_);
  // we_proj -> scattered wepr
  gemm_h16<3,0><<<dim3(G4_/128, (B_*T_)/128), 256, 0, stream>>>(
      we_h, E_, w_ih0_h, E_, nullptr, wepr, G4_, G4_, E_);
  // h0 = tanh(fcfeat @ fcproj^T + b) -> h_glob buf0
  gemm_h16<4,1><<<dim3(H_/128, B_/128), 256, 0, stream>>>(
      fcfeat_h, F_, fcproj_h, F_, fcproj_b, h_glob, H_, H_, F_);

  // ---- persistent column-parallel scan ----
  hipFuncSetAttribute((const void*)seq_loop, hipFuncAttributeMaxDynamicSharedMemorySize, SEQ_LDS);
  seq_loop<<<NBLK_, NTH_, SEQ_LDS, stream>>>(whhr, wa_r, base_glob, attproj_h,
                                             alpha_w, alpha_b, att_hb,
                                             attWr, wepr, h_glob, hp_glob, alpha_g,
                                             H_all_h, out + ALPHA_OFF, bar);

  // ---- logits ----
  gemm_h16<0,1><<<dim3(VP_/128, (B_*T_)/128), 256, 0, stream>>>(
      H_all_h, H_, fc_w_h, H_, fc_b, out, V_, V_, H_);
}